// Round 8
// baseline (566.656 us; speedup 1.0000x reference)
//
#include <hip/hip_runtime.h>
#include <stdint.h>

#define NUM_UNIQUE   256
#define NUM_SAMPLES  4096
#define NUM_QUBITS   64
#define BATCH_SIZE   1024
#define THREADS      1024
#define WAVES        (THREADS / 64)
#define CHUNKS       (NUM_SAMPLES / 64)      // 64 chunks of 64 samples
#define CHUNKS_PER_WAVE (CHUNKS / WAVES)     // 4
#define CHUNK_V4     1024                    // 64 samples * 64 qubits / 4 = v4i per chunk

typedef int v4i __attribute__((ext_vector_type(4)));

// Block = one unique circuit. 16 waves x 4 chunks of 64 samples.
// R8 = R7 resubmitted verbatim. R5/R6/R7 all died to "container failed
// twice" with materially different sources (R7 removed the outer unroll),
// while R4 — near-identical to R5 — ran fine: conclusively infra flake,
// not source-triggered. The experiment is still the first real test of
// cross-chunk register prefetch with the CORRECT 16 KB chunk stride.
// Prefetch: issue NEXT chunk's 16 dwordx4 loads (64 VGPRs in flight) before
// the ~1800-cycle transpose + pair loop; pack the buffer at iteration bottom.
__global__ __launch_bounds__(THREADS)
void energy_kernel(const int* __restrict__ samples,
                   const float* __restrict__ bias,
                   const float* __restrict__ Kmat,
                   float* __restrict__ uniq)
{
    __shared__ float Klds[NUM_QUBITS * 65];             // +1 pad: 2-way = free
    __shared__ unsigned long long words[WAVES][64];     // per-wave private
    __shared__ float wsum[WAVES];

    const int tid  = threadIdx.x;
    const int wave = tid >> 6;
    const int lane = tid & 63;
    const int c    = blockIdx.x;

    for (int t = tid; t < NUM_QUBITS * NUM_QUBITS; t += THREADS)
        Klds[(t >> 6) * 65 + (t & 63)] = Kmat[t];
    __syncthreads();

    const float* Krow = &Klds[lane * 65];
    float rowsum = 0.0f;
    #pragma unroll
    for (int r = 0; r < 64; ++r) rowsum += Krow[r];
    const float myBias = bias[lane];

    float pcacc = 0.0f;   // sum over chunks,r of K[q,r] * popcount(B_q^B_r)
    int   cnt   = 0;      // ones of qubit q over this wave's 256 samples

    const int loadrot  = (3 * wave + 5 * c) & 15;   // intra-chunk stagger
    const int chunkrot = (13 * c) & 63;             // chunk-order stagger

    const v4i* base = (const v4i*)(samples + (size_t)c * NUM_SAMPLES * NUM_QUBITS);

    v4i buf[16];                                    // 64 VGPRs of in-flight data

    // ---- prologue: load chunk 0 ----
    {
        const int chunk = ((wave * CHUNKS_PER_WAVE) + chunkrot) & 63;
        const v4i* cp = base + (size_t)chunk * CHUNK_V4;
        #pragma unroll
        for (int i = 0; i < 16; ++i) {
            const int j = (i + loadrot) & 15;
            buf[i] = __builtin_nontemporal_load(cp + j * 64 + lane);
        }
    }
    // pack chunk 0
    unsigned int m0 = 0, m1 = 0, m2 = 0, m3 = 0;
    #pragma unroll
    for (int i = 0; i < 16; ++i) {
        v4i v = buf[i];
        m0 = (m0 << 1) | (unsigned int)(v.x & 1);
        m1 = (m1 << 1) | (unsigned int)(v.y & 1);
        m2 = (m2 << 1) | (unsigned int)(v.z & 1);
        m3 = (m3 << 1) | (unsigned int)(v.w & 1);
    }
    unsigned long long W = (unsigned long long)m0
                         | ((unsigned long long)m1 << 16)
                         | ((unsigned long long)m2 << 32)
                         | ((unsigned long long)m3 << 48);

    for (int ci = 0; ci < CHUNKS_PER_WAVE; ++ci) {     // rolled (smaller body)
        // ---- issue NEXT chunk's loads; in flight across the pair loop ----
        if (ci + 1 < CHUNKS_PER_WAVE) {
            const int chunk = ((wave * CHUNKS_PER_WAVE + ci + 1) + chunkrot) & 63;
            const v4i* cp = base + (size_t)chunk * CHUNK_V4;
            #pragma unroll
            for (int i = 0; i < 16; ++i) {
                const int j = (i + loadrot) & 15;
                buf[i] = __builtin_nontemporal_load(cp + j * 64 + lane);
            }
        }

        // ---- 4-step shuffle transpose of current W: lane q gets B_q ----
        unsigned long long B = 0ull;
        #pragma unroll
        for (int p = 0; p < 4; ++p) {
            unsigned long long src = __shfl(W, 16 * p + (lane >> 2));
            B |= ((src >> (16 * (lane & 3))) & 0xFFFFull) << (16 * p);
        }

        cnt += (int)__popcll(B);
        words[wave][lane] = B;                   // same-wave write->read, no barrier

        // ---- Gram pair loop (no buf use -> no vmcnt wait inside) ----
        const unsigned long long* wp = words[wave];
        #pragma unroll
        for (int r = 0; r < 64; ++r) {
            unsigned long long br = wp[r];       // same-address broadcast
            int pc = (int)__popcll(B ^ br);
            pcacc = fmaf(Krow[r], (float)pc, pcacc);
        }

        // ---- pack the prefetched chunk (waitcnt lands here) ----
        if (ci + 1 < CHUNKS_PER_WAVE) {
            unsigned int n0 = 0, n1 = 0, n2 = 0, n3 = 0;
            #pragma unroll
            for (int i = 0; i < 16; ++i) {
                v4i v = buf[i];
                n0 = (n0 << 1) | (unsigned int)(v.x & 1);
                n1 = (n1 << 1) | (unsigned int)(v.y & 1);
                n2 = (n2 << 1) | (unsigned int)(v.z & 1);
                n3 = (n3 << 1) | (unsigned int)(v.w & 1);
            }
            W = (unsigned long long)n0
              | ((unsigned long long)n1 << 16)
              | ((unsigned long long)n2 << 32)
              | ((unsigned long long)n3 << 48);
        }
    }

    // quad: 64*nchunks*rowsum - 2*pcacc ; linear: bias_q * (256 - 2*cnt)
    float contrib = 64.0f * (float)CHUNKS_PER_WAVE * rowsum - 2.0f * pcacc
                  + myBias * (float)(CHUNKS_PER_WAVE * 64 - 2 * cnt);

    #pragma unroll
    for (int off = 32; off > 0; off >>= 1)
        contrib += __shfl_down(contrib, off);

    if (lane == 0) wsum[wave] = contrib;
    __syncthreads();
    if (tid == 0) {
        float s = 0.0f;
        #pragma unroll
        for (int i = 0; i < WAVES; ++i) s += wsum[i];
        uniq[c] = s * (1.0f / NUM_SAMPLES);
    }
}

__global__ void gather_kernel(const float* __restrict__ uniq,
                              const int* __restrict__ idx,
                              float* __restrict__ out)
{
    int b = blockIdx.x * blockDim.x + threadIdx.x;
    if (b < BATCH_SIZE) out[b] = uniq[idx[b]];
}

extern "C" void kernel_launch(void* const* d_in, const int* in_sizes, int n_in,
                              void* d_out, int out_size, void* d_ws, size_t ws_size,
                              hipStream_t stream)
{
    const int*   samples = (const int*)d_in[0];
    const int*   idx     = (const int*)d_in[1];
    const float* bias    = (const float*)d_in[2];
    const float* Kmat    = (const float*)d_in[3];
    float* out  = (float*)d_out;
    float* uniq = (float*)d_ws;   // 256 floats of scratch

    energy_kernel<<<NUM_UNIQUE, THREADS, 0, stream>>>(samples, bias, Kmat, uniq);
    gather_kernel<<<(BATCH_SIZE + 255) / 256, 256, 0, stream>>>(uniq, idx, out);
}

// Round 9
// 566.407 us; speedup vs baseline: 1.0004x; 1.0004x over previous
//
#include <hip/hip_runtime.h>
#include <stdint.h>

#define NUM_UNIQUE   256
#define NUM_SAMPLES  4096
#define NUM_QUBITS   64
#define BATCH_SIZE   1024
#define THREADS      1024
#define WAVES        (THREADS / 64)
#define CHUNKS       (NUM_SAMPLES / 64)      // 64 chunks of 64 samples
#define CHUNKS_PER_WAVE (CHUNKS / WAVES)     // 4
#define CHUNK_V4     1024                    // 64 samples * 64 qubits / 4 = v4i per chunk

typedef int v4i __attribute__((ext_vector_type(4)));

// Block = one unique circuit. 16 waves x 4 chunks of 64 samples.
// R9 = R8 + __launch_bounds__(1024, 4). R8's counters showed the compiler
// capped VGPRs at 64 (targeting 2 blocks/CU) and SPILLED the 64-VGPR
// prefetch buffer to scratch: WRITE_SIZE=648 MB on a ~5 KB-write kernel,
// FETCH 534 MB vs 263 MB ideal -> 1.2 GB traffic, 307 us. Declaring
// 4 waves/EU (= 1 block/CU for a 16-wave block) raises the cap to 128
// VGPR; buf[16]=64 + ~36 others fits with headroom. 16 waves/CU with
// 16 KB prefetched each = 256 KB in flight/CU — MLP, not occupancy,
// is what this kernel needs.
__global__ __launch_bounds__(THREADS, 4)
void energy_kernel(const int* __restrict__ samples,
                   const float* __restrict__ bias,
                   const float* __restrict__ Kmat,
                   float* __restrict__ uniq)
{
    __shared__ float Klds[NUM_QUBITS * 65];             // +1 pad: 2-way = free
    __shared__ unsigned long long words[WAVES][64];     // per-wave private
    __shared__ float wsum[WAVES];

    const int tid  = threadIdx.x;
    const int wave = tid >> 6;
    const int lane = tid & 63;
    const int c    = blockIdx.x;

    for (int t = tid; t < NUM_QUBITS * NUM_QUBITS; t += THREADS)
        Klds[(t >> 6) * 65 + (t & 63)] = Kmat[t];
    __syncthreads();

    const float* Krow = &Klds[lane * 65];
    float rowsum = 0.0f;
    #pragma unroll
    for (int r = 0; r < 64; ++r) rowsum += Krow[r];
    const float myBias = bias[lane];

    float pcacc = 0.0f;   // sum over chunks,r of K[q,r] * popcount(B_q^B_r)
    int   cnt   = 0;      // ones of qubit q over this wave's 256 samples

    const int loadrot  = (3 * wave + 5 * c) & 15;   // intra-chunk stagger
    const int chunkrot = (13 * c) & 63;             // chunk-order stagger

    const v4i* base = (const v4i*)(samples + (size_t)c * NUM_SAMPLES * NUM_QUBITS);

    v4i buf[16];                                    // 64 VGPRs of in-flight data

    // ---- prologue: load chunk 0 ----
    {
        const int chunk = ((wave * CHUNKS_PER_WAVE) + chunkrot) & 63;
        const v4i* cp = base + (size_t)chunk * CHUNK_V4;
        #pragma unroll
        for (int i = 0; i < 16; ++i) {
            const int j = (i + loadrot) & 15;
            buf[i] = __builtin_nontemporal_load(cp + j * 64 + lane);
        }
    }
    // pack chunk 0
    unsigned int m0 = 0, m1 = 0, m2 = 0, m3 = 0;
    #pragma unroll
    for (int i = 0; i < 16; ++i) {
        v4i v = buf[i];
        m0 = (m0 << 1) | (unsigned int)(v.x & 1);
        m1 = (m1 << 1) | (unsigned int)(v.y & 1);
        m2 = (m2 << 1) | (unsigned int)(v.z & 1);
        m3 = (m3 << 1) | (unsigned int)(v.w & 1);
    }
    unsigned long long W = (unsigned long long)m0
                         | ((unsigned long long)m1 << 16)
                         | ((unsigned long long)m2 << 32)
                         | ((unsigned long long)m3 << 48);

    for (int ci = 0; ci < CHUNKS_PER_WAVE; ++ci) {     // rolled (smaller body)
        // ---- issue NEXT chunk's loads; in flight across the pair loop ----
        if (ci + 1 < CHUNKS_PER_WAVE) {
            const int chunk = ((wave * CHUNKS_PER_WAVE + ci + 1) + chunkrot) & 63;
            const v4i* cp = base + (size_t)chunk * CHUNK_V4;
            #pragma unroll
            for (int i = 0; i < 16; ++i) {
                const int j = (i + loadrot) & 15;
                buf[i] = __builtin_nontemporal_load(cp + j * 64 + lane);
            }
        }

        // ---- 4-step shuffle transpose of current W: lane q gets B_q ----
        unsigned long long B = 0ull;
        #pragma unroll
        for (int p = 0; p < 4; ++p) {
            unsigned long long src = __shfl(W, 16 * p + (lane >> 2));
            B |= ((src >> (16 * (lane & 3))) & 0xFFFFull) << (16 * p);
        }

        cnt += (int)__popcll(B);
        words[wave][lane] = B;                   // same-wave write->read, no barrier

        // ---- Gram pair loop (no buf use -> no vmcnt wait inside) ----
        const unsigned long long* wp = words[wave];
        #pragma unroll
        for (int r = 0; r < 64; ++r) {
            unsigned long long br = wp[r];       // same-address broadcast
            int pc = (int)__popcll(B ^ br);
            pcacc = fmaf(Krow[r], (float)pc, pcacc);
        }

        // ---- pack the prefetched chunk (waitcnt lands here) ----
        if (ci + 1 < CHUNKS_PER_WAVE) {
            unsigned int n0 = 0, n1 = 0, n2 = 0, n3 = 0;
            #pragma unroll
            for (int i = 0; i < 16; ++i) {
                v4i v = buf[i];
                n0 = (n0 << 1) | (unsigned int)(v.x & 1);
                n1 = (n1 << 1) | (unsigned int)(v.y & 1);
                n2 = (n2 << 1) | (unsigned int)(v.z & 1);
                n3 = (n3 << 1) | (unsigned int)(v.w & 1);
            }
            W = (unsigned long long)n0
              | ((unsigned long long)n1 << 16)
              | ((unsigned long long)n2 << 32)
              | ((unsigned long long)n3 << 48);
        }
    }

    // quad: 64*nchunks*rowsum - 2*pcacc ; linear: bias_q * (256 - 2*cnt)
    float contrib = 64.0f * (float)CHUNKS_PER_WAVE * rowsum - 2.0f * pcacc
                  + myBias * (float)(CHUNKS_PER_WAVE * 64 - 2 * cnt);

    #pragma unroll
    for (int off = 32; off > 0; off >>= 1)
        contrib += __shfl_down(contrib, off);

    if (lane == 0) wsum[wave] = contrib;
    __syncthreads();
    if (tid == 0) {
        float s = 0.0f;
        #pragma unroll
        for (int i = 0; i < WAVES; ++i) s += wsum[i];
        uniq[c] = s * (1.0f / NUM_SAMPLES);
    }
}

__global__ void gather_kernel(const float* __restrict__ uniq,
                              const int* __restrict__ idx,
                              float* __restrict__ out)
{
    int b = blockIdx.x * blockDim.x + threadIdx.x;
    if (b < BATCH_SIZE) out[b] = uniq[idx[b]];
}

extern "C" void kernel_launch(void* const* d_in, const int* in_sizes, int n_in,
                              void* d_out, int out_size, void* d_ws, size_t ws_size,
                              hipStream_t stream)
{
    const int*   samples = (const int*)d_in[0];
    const int*   idx     = (const int*)d_in[1];
    const float* bias    = (const float*)d_in[2];
    const float* Kmat    = (const float*)d_in[3];
    float* out  = (float*)d_out;
    float* uniq = (float*)d_ws;   // 256 floats of scratch

    energy_kernel<<<NUM_UNIQUE, THREADS, 0, stream>>>(samples, bias, Kmat, uniq);
    gather_kernel<<<(BATCH_SIZE + 255) / 256, 256, 0, stream>>>(uniq, idx, out);
}